// Round 18
// baseline (112.024 us; speedup 1.0000x reference)
//
#include <hip/hip_runtime.h>
#include <math.h>

#define B_ 32
#define T_ 1024
#define C_ 801
#define L_ 128
#define S_ 257            // 2*L+1
#define BLANK 800
#define NEGV -1e30f

#define CH 128            // chunk rows
#define NCH (T_ / CH)     // 8 chunks
#define NWF 16            // waves per block: wave 0 computes, 1..15 stage
#define LN2F 0.69314718055994531f

// -------- DPP helpers --------
template <int CTRL>
__device__ __forceinline__ float dppf(float v) {
    return __uint_as_float((unsigned)__builtin_amdgcn_update_dpp(
        0, (int)__float_as_uint(v), CTRL, 0xf, 0xf, true));
}
__device__ __forceinline__ float shift_up1(float v) { return dppf<0x138>(v); }

__device__ __forceinline__ float wave_red_max63(float v) {
    v = fmaxf(v, dppf<0xB1>(v));
    v = fmaxf(v, dppf<0x4E>(v));
    v = fmaxf(v, dppf<0x141>(v));
    v = fmaxf(v, dppf<0x140>(v));
    v = fmaxf(v, dppf<0x142>(v));
    v = fmaxf(v, dppf<0x143>(v));
    return v;
}
__device__ __forceinline__ float wave_red_sum63(float v) {
    v += dppf<0xB1>(v);
    v += dppf<0x4E>(v);
    v += dppf<0x141>(v);
    v += dppf<0x140>(v);
    v += dppf<0x142>(v);
    v += dppf<0x143>(v);
    return v;
}
__device__ __forceinline__ float bcast63(float v) {
    return __uint_as_float((unsigned)__builtin_amdgcn_readlane((int)__float_as_uint(v), 63));
}
__device__ __forceinline__ float wave_max_nn(float v) { return bcast63(wave_red_max63(v)); }

__device__ __forceinline__ float bf16lo(unsigned u) { return __uint_as_float(u << 16); }
__device__ __forceinline__ float bf16hi(unsigned u) { return __uint_as_float(u & 0xFFFF0000u); }
__device__ __forceinline__ unsigned short f32_to_bf16_rne(float f) {
    unsigned u = __float_as_uint(f);
    u += 0x7FFF + ((u >> 16) & 1);
    return (unsigned short)(u >> 16);
}

#define RLANE(x, j) __uint_as_float((unsigned)__builtin_amdgcn_readlane((int)__float_as_uint(x), (j)))

__device__ __forceinline__ float tree_max13(const float* v) {
    float a = fmaxf(v[0], v[1]), b = fmaxf(v[2], v[3]), c = fmaxf(v[4], v[5]);
    float d = fmaxf(v[6], v[7]), e = fmaxf(v[8], v[9]), f = fmaxf(v[10], v[11]);
    return fmaxf(fmaxf(fmaxf(a, b), fmaxf(c, d)), fmaxf(fmaxf(e, f), v[12]));
}
__device__ __forceinline__ float tree_expsum13(const float* v, float m) {
    float e0 = __expf(v[0] - m),  e1 = __expf(v[1] - m),  e2 = __expf(v[2] - m);
    float e3 = __expf(v[3] - m),  e4 = __expf(v[4] - m),  e5 = __expf(v[5] - m);
    float e6 = __expf(v[6] - m),  e7 = __expf(v[7] - m),  e8 = __expf(v[8] - m);
    float e9 = __expf(v[9] - m),  eA = __expf(v[10] - m), eB = __expf(v[11] - m);
    float eC = __expf(v[12] - m);
    float a = (e0 + e1) + (e2 + e3), b = (e4 + e5) + (e6 + e7), c = (e8 + e9) + (eA + eB);
    return (a + b) + (c + eC);
}

// ================= Fused kernel: one block per batch =================
// Waves 1..15 produce emissions for chunk c+1 into LDS while wave 0 runs the
// recursion on chunk c. One __syncthreads per chunk.
__global__ __launch_bounds__(NWF * 64) void ctc_fused_kernel(const float* __restrict__ logits,
                                                             const int* __restrict__ labels,
                                                             const int* __restrict__ lens,
                                                             float* __restrict__ loss) {
    __shared__ unsigned ebuf[2][CH * 64];   // packed {bf16 e3, bf16 e1} per (row, lane): 2x32KB
    __shared__ float    bbuf[2][CH];        // blank emission per row (pre-scaled 2^10)

    const int b = blockIdx.x;
    const int tid = threadIdx.x;
    const int lane = tid & 63;
    const int wid = tid >> 6;
    const int ll = lens[b];
    const float* __restrict__ xb = logits + (size_t)b * T_ * C_;

    // per-lane label info (all waves; cheap)
    const int il1 = labels[b * L_ + 2 * lane];
    const int il3 = labels[b * L_ + 2 * lane + 1];
    const bool k1 = (2 * lane < ll), k3 = (2 * lane + 1 < ll);

    // ---- staging worker: compute one row's emissions into side sb ----
    // loads (v[] + label gathers) have no dependence on lse -> issue early together.
    struct Row { float v[13]; float g1, g3; };
    auto load_row = [&](int t, Row& R) {
        const float* x = xb + (size_t)t * C_;
        #pragma unroll
        for (int k = 0; k < 12; ++k) R.v[k] = x[lane + 64 * k];
        R.v[12] = (lane < 33) ? x[768 + lane] : NEGV;
        R.g1 = x[il1];
        R.g3 = x[il3];
    };
    auto emit_row = [&](int r, int sb, const Row& R) {
        float m = bcast63(wave_red_max63(tree_max13(R.v)));
        float s = bcast63(wave_red_sum63(tree_expsum13(R.v, m)));
        float lse = m + __logf(s);
        float e1 = k1 ? __expf(R.g1 - lse) * 1024.0f : 0.f;
        float e3 = k3 ? __expf(R.g3 - lse) * 1024.0f : 0.f;
        unsigned pack = ((unsigned)f32_to_bf16_rne(e3) << 16) | (unsigned)f32_to_bf16_rne(e1);
        ebuf[sb][r * 64 + lane] = pack;
        // blank logit = x[800] = v[12] of lane 32
        float blg = RLANE(R.v[12], 32);
        if (lane == 0) bbuf[sb][r] = __expf(blg - lse) * 1024.0f;
    };
    auto stage_chunk = [&](int cc, int sb) {
        // rows r = (wid-1) + 15k ; 2-deep software pipeline
        int r = wid - 1;
        Row cur, nxt;
        if (r < CH) load_row(cc * CH + r, cur);
        while (r < CH) {
            int rn = r + 15;
            if (rn < CH) load_row(cc * CH + rn, nxt);
            emit_row(r, sb, cur);
            cur = nxt;
            r = rn;
        }
    };

    // ---- recursion state (wave 0) ----
    float m21 = 0.f, m23 = 0.f, mask0 = 0.f, mask2 = 0.f, kq = 0.f;
    if (wid == 0) {
        int s1 = 4 * lane + 1;
        if (s1 >= 3) {
            int li = s1 >> 1;
            m21 = (labels[b * L_ + li] != labels[b * L_ + li - 1]) ? 1.f : 0.f;
        }
        int li3 = (4 * lane + 3) >> 1;
        m23 = (labels[b * L_ + li3] != labels[b * L_ + li3 - 1]) ? 1.f : 0.f;
        const int smax = 2 * ll + 1;
        mask0 = (4 * lane     < smax) ? 1.f : 0.f;
        mask2 = (4 * lane + 2 < smax) ? 1.f : 0.f;
        kq    = (ll == 128) ? 1.f : 0.f;
    }

    // prologue: waves 1..15 stage chunk 0 into side 0
    if (wid > 0) stage_chunk(0, 0);
    __syncthreads();

    float p0 = 0.f, p1 = 0.f, p2 = 0.f, p3 = 0.f, q = 0.f;
    if (wid == 0) {
        unsigned w0 = ebuf[0][lane];
        float eb0 = bbuf[0][0];
        p0 = (lane == 0) ? eb0 : 0.f;          // state 0 (blank), t=0
        p1 = (lane == 0) ? bf16lo(w0) : 0.f;   // state 1 (validity folded)
    }
    int E = 0;

    #pragma unroll 1
    for (int cc = 0; cc < NCH; ++cc) {
        const int cs = cc & 1;
        if (wid > 0) {
            if (cc + 1 < NCH) stage_chunk(cc + 1, cs ^ 1);
        } else {
            float ebv0 = bbuf[cs][lane];
            float ebv1 = bbuf[cs][64 + lane];
            const unsigned* bufp = ebuf[cs];
            #pragma unroll
            for (int g = 0; g < CH / 8; ++g) {
                unsigned u[8];
                #pragma unroll
                for (int k = 0; k < 8; ++k) u[k] = bufp[(g * 8 + k) * 64 + lane];
                #pragma unroll
                for (int k = 0; k < 8; ++k) {
                    if (cc == 0 && g == 0 && k == 0) continue;   // t=0 in init
                    const int j = g * 8 + k;
                    float ebt = (j < 64) ? RLANE(ebv0, j) : RLANE(ebv1, j - 64);
                    float el0 = bf16lo(u[k]);
                    float el1 = bf16hi(u[k]);
                    float ebm0 = ebt * mask0;
                    float ebm2 = ebt * mask2;
                    float eqm  = ebt * kq;
                    float shp3 = shift_up1(p3);
                    float n0 = (p0 + shp3) * ebm0;
                    float n1 = fmaf(m21, shp3, p1 + p0) * el0;
                    float n2 = (p2 + p1) * ebm2;
                    float n3 = fmaf(m23, p1, p3 + p2) * el1;
                    q = (q + p3) * eqm;
                    p0 = n0; p1 = n1; p2 = n2; p3 = n3;
                }
                // rescale every 8 steps (identical cadence)
                float mx = fmaxf(fmaxf(p0, p1), fmaxf(p2, fmaxf(p3, q)));
                mx = wave_max_nn(mx);
                int e2_ = (int)((__float_as_uint(mx) >> 23) & 0xFF) - 126;
                float sc_ = __uint_as_float((unsigned)(127 - e2_) << 23);
                p0 *= sc_; p1 *= sc_; p2 *= sc_; p3 *= sc_; q *= sc_;
                E += e2_;
            }
        }
        __syncthreads();
    }

    // termination: reuse ebuf[0] as f32 gather scratch
    float* pf = (float*)(&ebuf[0][0]);
    if (wid == 0) {
        *(float4*)(pf + 4 * lane) = make_float4(p0, p1, p2, p3);
        if (lane == 63) pf[256] = q;
    }
    __syncthreads();
    if (tid == 0) {
        float a1 = pf[2 * ll];
        float a2 = (ll > 0) ? pf[2 * ll - 1] : 0.f;
        loss[b] = -(__logf(a1 + a2) + ((float)E - 10240.0f) * LN2F);
    }
}

__global__ void mean_kernel(const float* __restrict__ loss, float* __restrict__ out) {
    if (threadIdx.x == 0) {
        float s = 0.f;
        for (int i = 0; i < B_; ++i) s += loss[i];
        out[0] = s / (float)B_;
    }
}

// ================= FALLBACK PATH (tiny ws; unchanged) =================

__global__ __launch_bounds__(256) void lse_kernel(const float* __restrict__ logits,
                                                  float* __restrict__ lse) {
    const int row = blockIdx.x;
    const float* __restrict__ x = logits + (size_t)row * C_;
    const int tid = threadIdx.x, lane = tid & 63, wid = tid >> 6;
    float v0 = x[tid], v1 = x[tid + 256], v2 = x[tid + 512];
    bool h3 = (tid + 768) < C_;
    float v3 = h3 ? x[tid + 768] : NEGV;
    float m = fmaxf(fmaxf(v0, v1), fmaxf(v2, v3));
    #pragma unroll
    for (int off = 32; off > 0; off >>= 1) m = fmaxf(m, __shfl_down(m, off));
    __shared__ float wred[4]; __shared__ float bm;
    if (lane == 0) wred[wid] = m;
    __syncthreads();
    if (tid == 0) bm = fmaxf(fmaxf(wred[0], wred[1]), fmaxf(wred[2], wred[3]));
    __syncthreads();
    m = bm;
    float s = __expf(v0 - m) + __expf(v1 - m) + __expf(v2 - m);
    if (h3) s += __expf(v3 - m);
    #pragma unroll
    for (int off = 32; off > 0; off >>= 1) s += __shfl_down(s, off);
    __syncthreads();
    if (lane == 0) wred[wid] = s;
    __syncthreads();
    if (tid == 0) lse[row] = m + __logf(wred[0] + wred[1] + wred[2] + wred[3]);
}

__global__ __launch_bounds__(320) void ctc_alpha_kernel(const float* __restrict__ logits,
                                                        const int* __restrict__ labels,
                                                        const int* __restrict__ lens,
                                                        const float* __restrict__ lse,
                                                        float* __restrict__ loss) {
    const int b = blockIdx.x;
    const int s = threadIdx.x;
    const int ll = lens[b];
    __shared__ float albuf[2][S_ + 2];
    if (s < 2) { albuf[0][s] = NEGV; albuf[1][s] = NEGV; }
    int cls = BLANK; bool allow2 = false;
    if (s < S_ && (s & 1)) {
        cls = labels[b * L_ + (s >> 1)];
        allow2 = (s >= 3) && (cls != labels[b * L_ + (s >> 1) - 1]);
    }
    const bool valid = (s < 2 * ll + 1);
    const float* __restrict__ xb = logits + (size_t)b * T_ * C_;
    const float* __restrict__ lseb = lse + b * T_;
    if (s < S_) {
        float e0 = xb[cls] - lseb[0];
        float a = (s == 0 || (s == 1 && ll > 0)) ? e0 : NEGV;
        if (!valid) a = NEGV;
        albuf[0][2 + s] = a;
    }
    __syncthreads();
    float e_next = xb[(size_t)C_ + cls];
    float lse_next = lseb[1];
    int cur = 0;
    for (int t = 1; t < T_; ++t) {
        const float e = e_next, lse_t = lse_next;
        if (t + 1 < T_) { e_next = xb[(size_t)(t + 1) * C_ + cls]; lse_next = lseb[t + 1]; }
        if (s < S_) {
            float a0 = albuf[cur][2 + s];
            float a1 = albuf[cur][1 + s];
            float a2 = allow2 ? albuf[cur][s] : NEGV;
            float m = fmaxf(fmaxf(a0, a1), a2);
            float r = m + __logf(__expf(a0 - m) + __expf(a1 - m) + __expf(a2 - m)) + (e - lse_t);
            if (!valid) r = NEGV;
            albuf[cur ^ 1][2 + s] = r;
        }
        __syncthreads();
        cur ^= 1;
    }
    if (s == 0) {
        float a1 = albuf[cur][2 + 2 * ll];
        float a2 = (ll > 0) ? albuf[cur][2 + 2 * ll - 1] : NEGV;
        float m = fmaxf(a1, a2);
        loss[b] = -(m + __logf(__expf(a1 - m) + __expf(a2 - m)));
    }
}

// ================= launch =================

extern "C" void kernel_launch(void* const* d_in, const int* in_sizes, int n_in,
                              void* d_out, int out_size, void* d_ws, size_t ws_size,
                              hipStream_t stream) {
    const float* logits = (const float*)d_in[0];
    const int*   labels = (const int*)d_in[1];
    const int*   lens   = (const int*)d_in[2];
    float* out = (float*)d_out;

    if (ws_size >= (size_t)B_ * sizeof(float)) {
        float* loss = (float*)d_ws;
        ctc_fused_kernel<<<B_, NWF * 64, 0, stream>>>(logits, labels, lens, loss);
        mean_kernel<<<1, 64, 0, stream>>>(loss, out);
    } else {
        float* lse  = (float*)d_ws;   // (unreachable in practice)
        float* loss = lse + (size_t)B_ * T_;
        lse_kernel<<<B_ * T_, 256, 0, stream>>>(logits, lse);
        ctc_alpha_kernel<<<B_, 320, 0, stream>>>(logits, labels, lens, lse, loss);
        mean_kernel<<<1, 64, 0, stream>>>(loss, out);
    }
}

// Round 19
// 73.102 us; speedup vs baseline: 1.5324x; 1.5324x over previous
//
#include <hip/hip_runtime.h>
#include <math.h>

#define B_ 32
#define T_ 1024
#define C_ 801
#define L_ 128
#define S_ 257            // 2*L+1
#define BLANK 800
#define NEGV -1e30f

#define CH 128            // chunk rows (labels-only: 256B/row -> 32KB/chunk)
#define NCH (T_ / CH)     // 8 chunks
#define NW 8              // waves per block (ctc kernel)
#define LN2F 0.69314718055994531f

typedef const unsigned __attribute__((address_space(1))) u32_g;
typedef unsigned __attribute__((address_space(3))) u32_l;

// -------- DPP helpers --------
template <int CTRL>
__device__ __forceinline__ float dppf(float v) {
    return __uint_as_float((unsigned)__builtin_amdgcn_update_dpp(
        0, (int)__float_as_uint(v), CTRL, 0xf, 0xf, true));
}
// lane l gets lane l-1's value; lane 0 gets 0.0f   [wave_shr:1]
__device__ __forceinline__ float shift_up1(float v) { return dppf<0x138>(v); }

// butterfly reduce; result valid in LANE 63 for ANY input values
__device__ __forceinline__ float wave_red_max63(float v) {
    v = fmaxf(v, dppf<0xB1>(v));    // xor1
    v = fmaxf(v, dppf<0x4E>(v));    // xor2
    v = fmaxf(v, dppf<0x141>(v));   // row_half_mirror (xor4)
    v = fmaxf(v, dppf<0x140>(v));   // row_mirror      (xor8)
    v = fmaxf(v, dppf<0x142>(v));   // row_bcast15
    v = fmaxf(v, dppf<0x143>(v));   // row_bcast31
    return v;
}
__device__ __forceinline__ float wave_red_sum63(float v) {
    v += dppf<0xB1>(v);
    v += dppf<0x4E>(v);
    v += dppf<0x141>(v);
    v += dppf<0x140>(v);
    v += dppf<0x142>(v);
    v += dppf<0x143>(v);
    return v;
}
__device__ __forceinline__ float bcast63(float v) {
    return __uint_as_float((unsigned)__builtin_amdgcn_readlane((int)__float_as_uint(v), 63));
}
__device__ __forceinline__ float wave_max_nn(float v) { return bcast63(wave_red_max63(v)); }

__device__ __forceinline__ float bf16lo(unsigned u) { return __uint_as_float(u << 16); }
__device__ __forceinline__ float bf16hi(unsigned u) { return __uint_as_float(u & 0xFFFF0000u); }
__device__ __forceinline__ unsigned short f32_to_bf16_rne(float f) {
    unsigned u = __float_as_uint(f);
    u += 0x7FFF + ((u >> 16) & 1);
    return (unsigned short)(u >> 16);
}

#define RLANE(x, j) __uint_as_float((unsigned)__builtin_amdgcn_readlane((int)__float_as_uint(x), (j)))

// ================= Kernel A: vectorized fused LSE + labels-only bf16 staging (R15) =========
// Block = 4 rows (12816 B, float4-aligned). el[row][lane] = packed {bf16 el3, bf16 el1}
// (odd-state validity folded; pre-scaled 2^10). ebq[row] = f32 blank emission (pre-scaled).
__global__ __launch_bounds__(256) void stage_kernel(const float* __restrict__ logits,
                                                    const int* __restrict__ labels,
                                                    const int* __restrict__ lens,
                                                    unsigned* __restrict__ ea32,
                                                    float* __restrict__ ebq) {
    const int tid = threadIdx.x, lane = tid & 63, wv = tid >> 6;
    const int b = blockIdx.y;
    const int t0 = blockIdx.x * 4;
    const float* __restrict__ base = logits + ((size_t)b * T_ + t0) * C_;  // 16B-aligned
    __shared__ float xs[4 * C_];

    const float4* src = (const float4*)base;
    #pragma unroll
    for (int k = 0; k < 4; ++k) {
        int idx = tid + 256 * k;
        if (idx < 801) ((float4*)xs)[idx] = src[idx];
    }
    __syncthreads();

    const float* xr = xs + wv * C_;
    float v[13];
    float m = NEGV;
    #pragma unroll
    for (int k = 0; k < 12; ++k) { v[k] = xr[lane + 64 * k]; m = fmaxf(m, v[k]); }
    v[12] = (lane < 33) ? xr[768 + lane] : NEGV;
    m = fmaxf(m, v[12]);
    m = bcast63(wave_red_max63(m));

    float s = 0.f;
    #pragma unroll
    for (int k = 0; k < 13; ++k) s += __expf(v[k] - m);
    s = bcast63(wave_red_sum63(s));
    const float lse = m + __logf(s);

    const int ll = lens[b];
    const int row = b * T_ + (t0 + wv);
    const float ebl = __expf(xr[BLANK] - lse) * 1024.0f;
    const int cls1 = labels[b * L_ + 2 * lane];
    const int cls3 = labels[b * L_ + 2 * lane + 1];
    float e1 = (2 * lane     < ll) ? __expf(xr[cls1] - lse) * 1024.0f : 0.f;
    float e3 = (2 * lane + 1 < ll) ? __expf(xr[cls3] - lse) * 1024.0f : 0.f;

    unsigned pack = ((unsigned)f32_to_bf16_rne(e3) << 16) | (unsigned)f32_to_bf16_rne(e1);
    ea32[(size_t)row * 64 + lane] = pack;      // fully coalesced 4B/lane
    if (lane == 0) ebq[row] = ebl;
}

// ================= Kernel B helpers =================

__device__ __forceinline__ void stage_chunk_split(const unsigned* gbase, int c,
                                                  unsigned* lbase, int lane, int wid) {
    #pragma unroll
    for (int k = 0; k < CH / NW; ++k) {
        int r = wid + k * NW;
        const unsigned* gp = gbase + ((size_t)(c * CH + r)) * 64 + lane;  // per-lane 4B
        unsigned* lp = lbase + r * 64;                                    // wave-uniform dest
        __builtin_amdgcn_global_load_lds((u32_g*)gp, (u32_l*)lp, 4, 0, 0);
    }
}

// Software-pipelined: group g+1's 8 ds_read_b32 issue BEFORE group g's 8 dependent steps.
template <int FIRST>
__device__ __forceinline__ void compute_chunk(const unsigned* bufp, float ebv0, float ebv1,
                                              int lane, float m21, float m23,
                                              float mask0, float mask2, float kq,
                                              float& p0, float& p1, float& p2, float& p3,
                                              float& q, int& E) {
    unsigned u[8], un[8];
    #pragma unroll
    for (int k = 0; k < 8; ++k) u[k] = bufp[k * 64 + lane];
    #pragma unroll
    for (int g = 0; g < CH / 8; ++g) {
        if (g + 1 < CH / 8) {
            #pragma unroll
            for (int k = 0; k < 8; ++k) un[k] = bufp[((g + 1) * 8 + k) * 64 + lane];
        }
        #pragma unroll
        for (int k = 0; k < 8; ++k) {
            if (FIRST && g == 0 && k == 0) continue;   // t=0 handled by init
            const int j = g * 8 + k;
            float ebt = (j < 64) ? RLANE(ebv0, j) : RLANE(ebv1, j - 64);
            float el0 = bf16lo(u[k]);
            float el1 = bf16hi(u[k]);
            float ebm0 = ebt * mask0;
            float ebm2 = ebt * mask2;
            float eqm  = ebt * kq;
            float shp3 = shift_up1(p3);
            float n0 = (p0 + shp3) * ebm0;
            float n1 = fmaf(m21, shp3, p1 + p0) * el0;
            float n2 = (p2 + p1) * ebm2;
            float n3 = fmaf(m23, p1, p3 + p2) * el1;
            q = (q + p3) * eqm;
            p0 = n0; p1 = n1; p2 = n2; p3 = n3;
        }
        // rescale after steps 7,15,... (identical cadence)
        float mx = fmaxf(fmaxf(p0, p1), fmaxf(p2, fmaxf(p3, q)));
        mx = wave_max_nn(mx);
        int e2_ = (int)((__float_as_uint(mx) >> 23) & 0xFF) - 126;
        float sc_ = __uint_as_float((unsigned)(127 - e2_) << 23);
        p0 *= sc_; p1 *= sc_; p2 *= sc_; p3 *= sc_; q *= sc_;
        E += e2_;
        #pragma unroll
        for (int k = 0; k < 8; ++k) u[k] = un[k];   // register rename, no code
    }
}

// ================= Kernel B: linear CTC forward =================
// 8 waves co-issue the chunk DMA; wave 0 computes. ONLY fence: __syncthreads().
__global__ __launch_bounds__(NW * 64) void ctc_lds_kernel(const unsigned* __restrict__ ea32,
                                                          const float* __restrict__ ebq,
                                                          const int* __restrict__ labels,
                                                          const int* __restrict__ lens,
                                                          float* __restrict__ loss) {
    __shared__ unsigned buf[2][CH * 64];   // 2 x 32 KB
    const int b = blockIdx.x;
    const int tid = threadIdx.x;
    const int lane = tid & 63;
    const int wid = tid >> 6;
    const int ll = lens[b];
    const unsigned* gbase = ea32 + (size_t)b * T_ * 64;
    const float* qb = ebq + b * T_;

    float m21 = 0.f, m23 = 0.f, mask0 = 0.f, mask2 = 0.f, kq = 0.f;
    if (wid == 0) {
        int s1 = 4 * lane + 1;
        if (s1 >= 3) {
            int li = s1 >> 1;
            m21 = (labels[b * L_ + li] != labels[b * L_ + li - 1]) ? 1.f : 0.f;
        }
        int li3 = (4 * lane + 3) >> 1;
        m23 = (labels[b * L_ + li3] != labels[b * L_ + li3 - 1]) ? 1.f : 0.f;
        const int smax = 2 * ll + 1;
        mask0 = (4 * lane     < smax) ? 1.f : 0.f;
        mask2 = (4 * lane + 2 < smax) ? 1.f : 0.f;
        kq    = (ll == 128) ? 1.f : 0.f;
    }

    stage_chunk_split(gbase, 0, buf[0], lane, wid);
    float ebv0 = 0.f, ebv1 = 0.f, ebn0 = 0.f, ebn1 = 0.f;
    if (wid == 0) { ebv0 = qb[lane]; ebv1 = qb[64 + lane]; }
    __syncthreads();

    float p0 = 0.f, p1 = 0.f, p2 = 0.f, p3 = 0.f, q = 0.f;
    if (wid == 0) {
        float eb0 = RLANE(ebv0, 0);
        unsigned w0 = buf[0][lane];
        p0 = (lane == 0) ? eb0 : 0.f;
        p1 = (lane == 0) ? bf16lo(w0) : 0.f;
    }
    int E = 0;

    #pragma unroll 1
    for (int c = 0; c < NCH; ++c) {
        if (c + 1 < NCH) {
            stage_chunk_split(gbase, c + 1, buf[(c + 1) & 1], lane, wid);
            if (wid == 0) { ebn0 = qb[(c + 1) * CH + lane]; ebn1 = qb[(c + 1) * CH + 64 + lane]; }
        }
        if (wid == 0) {
            if (c == 0) compute_chunk<1>(buf[0],     ebv0, ebv1, lane, m21, m23,
                                         mask0, mask2, kq, p0, p1, p2, p3, q, E);
            else        compute_chunk<0>(buf[c & 1], ebv0, ebv1, lane, m21, m23,
                                         mask0, mask2, kq, p0, p1, p2, p3, q, E);
            ebv0 = ebn0; ebv1 = ebn1;
        }
        __syncthreads();
    }

    float* pf = (float*)(&buf[0][0]);
    if (wid == 0) {
        *(float4*)(pf + 4 * lane) = make_float4(p0, p1, p2, p3);
        if (lane == 63) pf[256] = q;
    }
    __syncthreads();
    if (tid == 0) {
        float a1 = pf[2 * ll];
        float a2 = (ll > 0) ? pf[2 * ll - 1] : 0.f;
        loss[b] = -(__logf(a1 + a2) + ((float)E - 10240.0f) * LN2F);
    }
}

__global__ void mean_kernel(const float* __restrict__ loss, float* __restrict__ out) {
    if (threadIdx.x == 0) {
        float s = 0.f;
        for (int i = 0; i < B_; ++i) s += loss[i];
        out[0] = s / (float)B_;
    }
}

// ================= FALLBACK PATH (tiny ws; unchanged) =================

__global__ __launch_bounds__(256) void lse_kernel(const float* __restrict__ logits,
                                                  float* __restrict__ lse) {
    const int row = blockIdx.x;
    const float* __restrict__ x = logits + (size_t)row * C_;
    const int tid = threadIdx.x, lane = tid & 63, wid = tid >> 6;
    float v0 = x[tid], v1 = x[tid + 256], v2 = x[tid + 512];
    bool h3 = (tid + 768) < C_;
    float v3 = h3 ? x[tid + 768] : NEGV;
    float m = fmaxf(fmaxf(v0, v1), fmaxf(v2, v3));
    #pragma unroll
    for (int off = 32; off > 0; off >>= 1) m = fmaxf(m, __shfl_down(m, off));
    __shared__ float wred[4]; __shared__ float bm;
    if (lane == 0) wred[wid] = m;
    __syncthreads();
    if (tid == 0) bm = fmaxf(fmaxf(wred[0], wred[1]), fmaxf(wred[2], wred[3]));
    __syncthreads();
    m = bm;
    float s = __expf(v0 - m) + __expf(v1 - m) + __expf(v2 - m);
    if (h3) s += __expf(v3 - m);
    #pragma unroll
    for (int off = 32; off > 0; off >>= 1) s += __shfl_down(s, off);
    __syncthreads();
    if (lane == 0) wred[wid] = s;
    __syncthreads();
    if (tid == 0) lse[row] = m + __logf(wred[0] + wred[1] + wred[2] + wred[3]);
}

__global__ __launch_bounds__(320) void ctc_alpha_kernel(const float* __restrict__ logits,
                                                        const int* __restrict__ labels,
                                                        const int* __restrict__ lens,
                                                        const float* __restrict__ lse,
                                                        float* __restrict__ loss) {
    const int b = blockIdx.x;
    const int s = threadIdx.x;
    const int ll = lens[b];
    __shared__ float albuf[2][S_ + 2];
    if (s < 2) { albuf[0][s] = NEGV; albuf[1][s] = NEGV; }
    int cls = BLANK; bool allow2 = false;
    if (s < S_ && (s & 1)) {
        cls = labels[b * L_ + (s >> 1)];
        allow2 = (s >= 3) && (cls != labels[b * L_ + (s >> 1) - 1]);
    }
    const bool valid = (s < 2 * ll + 1);
    const float* __restrict__ xb = logits + (size_t)b * T_ * C_;
    const float* __restrict__ lseb = lse + b * T_;
    if (s < S_) {
        float e0 = xb[cls] - lseb[0];
        float a = (s == 0 || (s == 1 && ll > 0)) ? e0 : NEGV;
        if (!valid) a = NEGV;
        albuf[0][2 + s] = a;
    }
    __syncthreads();
    float e_next = xb[(size_t)C_ + cls];
    float lse_next = lseb[1];
    int cur = 0;
    for (int t = 1; t < T_; ++t) {
        const float e = e_next, lse_t = lse_next;
        if (t + 1 < T_) { e_next = xb[(size_t)(t + 1) * C_ + cls]; lse_next = lseb[t + 1]; }
        if (s < S_) {
            float a0 = albuf[cur][2 + s];
            float a1 = albuf[cur][1 + s];
            float a2 = allow2 ? albuf[cur][s] : NEGV;
            float m = fmaxf(fmaxf(a0, a1), a2);
            float r = m + __logf(__expf(a0 - m) + __expf(a1 - m) + __expf(a2 - m)) + (e - lse_t);
            if (!valid) r = NEGV;
            albuf[cur ^ 1][2 + s] = r;
        }
        __syncthreads();
        cur ^= 1;
    }
    if (s == 0) {
        float a1 = albuf[cur][2 + 2 * ll];
        float a2 = (ll > 0) ? albuf[cur][2 + 2 * ll - 1] : NEGV;
        float m = fmaxf(a1, a2);
        loss[b] = -(m + __logf(__expf(a1 - m) + __expf(a2 - m)));
    }
}

// ================= launch =================

extern "C" void kernel_launch(void* const* d_in, const int* in_sizes, int n_in,
                              void* d_out, int out_size, void* d_ws, size_t ws_size,
                              hipStream_t stream) {
    const float* logits = (const float*)d_in[0];
    const int*   labels = (const int*)d_in[1];
    const int*   lens   = (const int*)d_in[2];
    float* out = (float*)d_out;

    const size_t ea_elems = (size_t)B_ * T_ * 64;            // uints (packed bf16 pairs)
    const size_t eb_elems = (size_t)B_ * T_;                 // floats
    const size_t need = (ea_elems + eb_elems + B_) * 4;

    if (ws_size >= need) {
        unsigned* ea32 = (unsigned*)d_ws;
        float* ebq  = (float*)(ea32 + ea_elems);
        float* loss = ebq + eb_elems;
        dim3 grid(T_ / 4, B_);
        stage_kernel<<<grid, 256, 0, stream>>>(logits, labels, lens, ea32, ebq);
        ctc_lds_kernel<<<B_, NW * 64, 0, stream>>>(ea32, ebq, labels, lens, loss);
        mean_kernel<<<1, 64, 0, stream>>>(loss, out);
    } else {
        float* lse  = (float*)d_ws;
        float* loss = lse + (size_t)B_ * T_;
        lse_kernel<<<B_ * T_, 256, 0, stream>>>(logits, lse);
        ctc_alpha_kernel<<<B_, 320, 0, stream>>>(logits, labels, lens, lse, loss);
        mean_kernel<<<1, 64, 0, stream>>>(loss, out);
    }
}